// Round 2
// baseline (367.241 us; speedup 1.0000x reference)
//
#include <hip/hip_runtime.h>

// TypedCoords2Volume — GATHER formulation.
// Instead of zero-fill (304MB write) + atomic scatter (RMW), we bin atoms by
// (x,y) cell-bin and then write every output voxel exactly once: each thread
// owns one (b,x,y,z) column over all 11 types, sums Gaussian contributions of
// candidate atoms from <=4 neighboring bins. One coalesced 304MB write pass.

#define BOX    120
#define NTYPES 11
#define DHALF  2
#define BOX3   (BOX * BOX * BOX)

#define BINSZ   4              // cells per bin (x and y)
#define NBIN    30             // BOX / BINSZ
#define NBIN2   (NBIN * NBIN)
#define CAP     64             // max atoms stored per (x,y) bin column

// ---------------------------------------------------------------------------
// Zero the per-bin atom counters (d_ws is poisoned 0xAA before every launch).
// ---------------------------------------------------------------------------
__global__ void zero_counts_kernel(int* __restrict__ counts, int n) {
    int i = blockIdx.x * blockDim.x + threadIdx.x;
    if (i < n) counts[i] = 0;
}

// ---------------------------------------------------------------------------
// Bin atoms: one thread per (b, atom). Resolves type/validity, computes the
// base cell, and appends (x, y, z, type) to the (bx>>2, by>>2) bin.
// ---------------------------------------------------------------------------
__global__ void bin_kernel(const float* __restrict__ coords,
                           const int*  __restrict__ num_atoms_of_type,
                           const int*  __restrict__ offsets,
                           float4* __restrict__ bins,
                           int*    __restrict__ counts,
                           int batch, int natoms) {
    int gid = blockIdx.x * blockDim.x + threadIdx.x;
    if (gid >= batch * natoms) return;
    int b = gid / natoms;
    int i = gid - b * natoms;

    const float* c = coords + ((long long)b * natoms + i) * 3;
    float x = c[0], y = c[1], z = c[2];

    const int* off = offsets           + b * NTYPES;
    const int* num = num_atoms_of_type + b * NTYPES;

    // t = clip(searchsorted(off, i, 'right') - 1, 0, NTYPES-1)
    int t = 0;
#pragma unroll
    for (int k = 1; k < NTYPES; ++k)
        if (off[k] <= i) t = k;
    if (!(i >= off[t] && i < off[t] + num[t])) return;

    int bx = (int)floorf(x);
    int by = (int)floorf(y);
    int bz = (int)floorf(z);
    // atoms whose window cannot intersect the box contribute nothing
    if (bx < -DHALF || bx >= BOX + DHALF ||
        by < -DHALF || by >= BOX + DHALF ||
        bz < -DHALF || bz >= BOX + DHALF) return;

    int cbx = min(BOX - 1, max(0, bx)) / BINSZ;
    int cby = min(BOX - 1, max(0, by)) / BINSZ;
    int bin = b * NBIN2 + cbx * NBIN + cby;

    int slot = atomicAdd(&counts[bin], 1);
    if (slot < CAP)
        bins[(long long)bin * CAP + slot] =
            make_float4(x, y, z, __int_as_float(t));
}

// ---------------------------------------------------------------------------
// Gather: one block per (b, x, y); 128 threads, lane = z (120 active).
// Scans atoms in the <=2x2 neighboring (x,y) bins; exact window test
// |voxel - floor(coord)| <= 2 per dim reproduces the scatter semantics.
// Accumulates into 11 per-type registers (constant-indexed), writes 11 floats.
// ---------------------------------------------------------------------------
__global__ void gather_kernel(const float4* __restrict__ bins,
                              const int*    __restrict__ counts,
                              float* __restrict__ out) {
    int bid = blockIdx.x;
    int y = bid % BOX; bid /= BOX;
    int x = bid % BOX; bid /= BOX;
    int b = bid;
    int z = threadIdx.x;
    bool zon = (z < BOX);

    float acc[NTYPES];
#pragma unroll
    for (int k = 0; k < NTYPES; ++k) acc[k] = 0.f;

    int bx0 = max(0, x - DHALF) / BINSZ;
    int bx1 = min(BOX - 1, x + DHALF) / BINSZ;
    int by0 = max(0, y - DHALF) / BINSZ;
    int by1 = min(BOX - 1, y + DHALF) / BINSZ;

    for (int cbx = bx0; cbx <= bx1; ++cbx) {
        for (int cby = by0; cby <= by1; ++cby) {
            int bin = b * NBIN2 + cbx * NBIN + cby;
            int cnt = min(counts[bin], CAP);
            const float4* lst = bins + (long long)bin * CAP;
            for (int j = 0; j < cnt; ++j) {
                float4 a = lst[j];
                int abx = (int)floorf(a.x);
                int aby = (int)floorf(a.y);
                int abz = (int)floorf(a.z);
                // window membership on BASE cell (matches scatter win offsets)
                if (abs(x - abx) > DHALF || abs(y - aby) > DHALF) continue;
                bool hit = zon && (abs(z - abz) <= DHALF);
                float dx = (float)x - a.x;
                float dy = (float)y - a.y;
                float dz = (float)z - a.z;
                float r2 = dx * dx + dy * dy + dz * dz;
                float val = hit ? expf(-r2) : 0.f;
                int t = __float_as_int(a.w);
#pragma unroll
                for (int k = 0; k < NTYPES; ++k)
                    acc[k] += (t == k) ? val : 0.f;
            }
        }
    }

    if (zon) {
        int base = x * (BOX * BOX) + y * BOX + z;
#pragma unroll
        for (int k = 0; k < NTYPES; ++k)
            out[(long long)(b * NTYPES + k) * BOX3 + base] = acc[k];
    }
}

// ---------------------------------------------------------------------------
extern "C" void kernel_launch(void* const* d_in, const int* in_sizes, int n_in,
                              void* d_out, int out_size, void* d_ws, size_t ws_size,
                              hipStream_t stream) {
    const float* coords = (const float*)d_in[0];
    const int*   num    = (const int*)d_in[1];
    const int*   off    = (const int*)d_in[2];
    float*       out    = (float*)d_out;

    int batch  = in_sizes[1] / NTYPES;        // [B, NTYPES]
    int natoms = in_sizes[0] / (3 * batch);   // [B, NATOMS*3]

    // workspace layout: [counts: batch*NBIN2 ints][bins: batch*NBIN2*CAP float4]
    int    nbins  = batch * NBIN2;
    int*   counts = (int*)d_ws;
    size_t bins_off = ((size_t)nbins * sizeof(int) + 15) & ~(size_t)15;
    float4* bins  = (float4*)((char*)d_ws + bins_off);

    zero_counts_kernel<<<(nbins + 255) / 256, 256, 0, stream>>>(counts, nbins);

    int natom_threads = batch * natoms;
    bin_kernel<<<(natom_threads + 255) / 256, 256, 0, stream>>>(
        coords, num, off, bins, counts, batch, natoms);

    gather_kernel<<<batch * BOX * BOX, 128, 0, stream>>>(bins, counts, out);
}

// Round 4
// 324.133 us; speedup vs baseline: 1.1330x; 1.1330x over previous
//
#include <hip/hip_runtime.h>

// TypedCoords2Volume — gather with full-cache-line-aligned writes.
// Pipeline: zero bin counters -> bin atoms by (x,y) 4x4 cell bins ->
// gather: one block per (b, x, y-tile of 8). Threads own (y_local, z/4)
// and write float4 per type; every 128B line of the 304MB output is written
// exactly once, fully, by a single wave (block writes 3840B-aligned chunks).
// Candidate atoms staged to LDS and counting-sorted by type so the
// accumulator acc[11][4] is always compile-time indexed (stays in VGPRs).

#define BOX    120
#define NTYPES 11
#define DHALF  2
#define BOX3   (BOX * BOX * BOX)

#define BINSZ  4
#define NBIN   30              // BOX / BINSZ
#define NBIN2  (NBIN * NBIN)
#define CAP    64              // atoms per (x,y) bin column

#define YT     8               // y-rows per gather block
#define NYT    (BOX / YT)      // 15
#define SCAP   512             // staged-atom cap per block (avg ~9, max ~30)

// ---------------------------------------------------------------------------
__global__ void zero_counts_kernel(int* __restrict__ counts, int n) {
    int i = blockIdx.x * blockDim.x + threadIdx.x;
    if (i < n) counts[i] = 0;
}

// ---------------------------------------------------------------------------
// Bin atoms (unchanged from validated r2 kernel).
// ---------------------------------------------------------------------------
__global__ void bin_kernel(const float* __restrict__ coords,
                           const int*  __restrict__ num_atoms_of_type,
                           const int*  __restrict__ offsets,
                           float4* __restrict__ bins,
                           int*    __restrict__ counts,
                           int batch, int natoms) {
    int gid = blockIdx.x * blockDim.x + threadIdx.x;
    if (gid >= batch * natoms) return;
    int b = gid / natoms;
    int i = gid - b * natoms;

    const float* c = coords + ((long long)b * natoms + i) * 3;
    float x = c[0], y = c[1], z = c[2];

    const int* off = offsets           + b * NTYPES;
    const int* num = num_atoms_of_type + b * NTYPES;

    int t = 0;
#pragma unroll
    for (int k = 1; k < NTYPES; ++k)
        if (off[k] <= i) t = k;
    if (!(i >= off[t] && i < off[t] + num[t])) return;

    int bx = (int)floorf(x);
    int by = (int)floorf(y);
    int bz = (int)floorf(z);
    if (bx < -DHALF || bx >= BOX + DHALF ||
        by < -DHALF || by >= BOX + DHALF ||
        bz < -DHALF || bz >= BOX + DHALF) return;

    int cbx = min(BOX - 1, max(0, bx)) / BINSZ;
    int cby = min(BOX - 1, max(0, by)) / BINSZ;
    int bin = b * NBIN2 + cbx * NBIN + cby;

    int slot = atomicAdd(&counts[bin], 1);
    if (slot < CAP)
        bins[(long long)bin * CAP + slot] =
            make_float4(x, y, z, __int_as_float(t));
}

// ---------------------------------------------------------------------------
// Gather. Block = (b, x, yt). 256 threads; thread t<240: yl=t/30, z4=t%30.
// ---------------------------------------------------------------------------
__global__ __launch_bounds__(256)
void gather_kernel(const float4* __restrict__ bins,
                   const int*    __restrict__ counts,
                   float* __restrict__ out) {
    int bid = blockIdx.x;
    int yt = bid % NYT; bid /= NYT;
    int x  = bid % BOX; bid /= BOX;
    int b  = bid;
    int y0 = yt * YT;
    float xf = (float)x;

    __shared__ float4 raw[SCAP];
    __shared__ float4 srt[SCAP];
    __shared__ int cnt;
    __shared__ int tcnt[NTYPES];
    __shared__ int tstart[NTYPES + 1];
    __shared__ int tidx[NTYPES];

    if (threadIdx.x == 0) cnt = 0;
    if (threadIdx.x < NTYPES) tcnt[threadIdx.x] = 0;
    __syncthreads();

    // ---- stage candidate atoms from the <=8 neighboring bins ----
    int bxlo = max(0, x - DHALF) / BINSZ;
    int bxhi = min(BOX - 1, x + DHALF) / BINSZ;
    int bylo = max(0, y0 - DHALF) / BINSZ;
    int byhi = min(BOX - 1, y0 + YT - 1 + DHALF) / BINSZ;

    for (int cbx = bxlo; cbx <= bxhi; ++cbx) {
        for (int cby = bylo; cby <= byhi; ++cby) {
            int bin = b * NBIN2 + cbx * NBIN + cby;
            int c = min(counts[bin], CAP);
            const float4* lst = bins + (long long)bin * CAP;
            for (int j = threadIdx.x; j < c; j += blockDim.x) {
                float4 a = lst[j];
                float abx = floorf(a.x);
                float aby = floorf(a.y);
                // exact x window (block-uniform x) and y-tile window
                if (fabsf(xf - abx) <= (float)DHALF &&
                    aby >= (float)(y0 - DHALF) &&
                    aby <= (float)(y0 + YT - 1 + DHALF)) {
                    int slot = atomicAdd(&cnt, 1);
                    if (slot < SCAP) {
                        int t = __float_as_int(a.w);
                        atomicAdd(&tcnt[t], 1);
                        float dx = xf - a.x;
                        raw[slot] = make_float4(a.y, a.z, dx * dx, a.w);
                    }
                }
            }
        }
    }
    __syncthreads();

    int n = min(cnt, SCAP);
    if (threadIdx.x == 0) {
        int s = 0;
#pragma unroll
        for (int k = 0; k < NTYPES; ++k) {
            tstart[k] = s; tidx[k] = s; s += tcnt[k];
        }
        tstart[NTYPES] = s;
    }
    __syncthreads();

    // counting-sort by type
    for (int j = threadIdx.x; j < n; j += blockDim.x) {
        float4 a = raw[j];
        int t = __float_as_int(a.w);
        int d = atomicAdd(&tidx[t], 1);
        srt[d] = a;
    }
    __syncthreads();

    // ---- accumulate: thread owns (yl, 4 z voxels) across all 11 types ----
    int tt = threadIdx.x;
    int yl = tt / 30;
    int z4 = tt - yl * 30;
    bool on = (tt < 240);
    float yf  = (float)(y0 + yl);
    float zf0 = (float)(z4 * 4);

    float acc[NTYPES][4];
#pragma unroll
    for (int k = 0; k < NTYPES; ++k)
#pragma unroll
        for (int i = 0; i < 4; ++i) acc[k][i] = 0.f;

#pragma unroll
    for (int k = 0; k < NTYPES; ++k) {
        int s = tstart[k], e = tstart[k + 1];
        for (int j = s; j < e; ++j) {
            float4 a = srt[j];              // (ay, az, dx2, type)
            float ay = a.x, az = a.y, dx2 = a.z;
            float aby = floorf(ay);
            float abz = floorf(az);
            bool yok = fabsf(yf - aby) <= (float)DHALF;
            float dy  = yf - ay;
            float c2  = fmaf(dy, dy, dx2);
            float dz0  = zf0 - az;
            float dzc0 = zf0 - abz;
#pragma unroll
            for (int i = 0; i < 4; ++i) {
                float dz = dz0 + (float)i;
                float r2 = fmaf(dz, dz, c2);
                bool zok = fabsf(dzc0 + (float)i) <= (float)DHALF;
                float v = (yok && zok) ? expf(-r2) : 0.f;
                acc[k][i] += v;
            }
        }
    }

    // ---- write: 11 aligned float4 stores, all lines fully covered ----
    if (on) {
        int base = x * (BOX * BOX) + (y0 + yl) * BOX + z4 * 4;
#pragma unroll
        for (int k = 0; k < NTYPES; ++k) {
            float4 v = make_float4(acc[k][0], acc[k][1], acc[k][2], acc[k][3]);
            *reinterpret_cast<float4*>(&out[(long long)(b * NTYPES + k) * BOX3 + base]) = v;
        }
    }
}

// ---------------------------------------------------------------------------
extern "C" void kernel_launch(void* const* d_in, const int* in_sizes, int n_in,
                              void* d_out, int out_size, void* d_ws, size_t ws_size,
                              hipStream_t stream) {
    const float* coords = (const float*)d_in[0];
    const int*   num    = (const int*)d_in[1];
    const int*   off    = (const int*)d_in[2];
    float*       out    = (float*)d_out;

    int batch  = in_sizes[1] / NTYPES;        // [B, NTYPES]
    int natoms = in_sizes[0] / (3 * batch);   // [B, NATOMS*3]

    int    nbins  = batch * NBIN2;
    int*   counts = (int*)d_ws;
    size_t bins_off = ((size_t)nbins * sizeof(int) + 15) & ~(size_t)15;
    float4* bins  = (float4*)((char*)d_ws + bins_off);

    zero_counts_kernel<<<(nbins + 255) / 256, 256, 0, stream>>>(counts, nbins);

    int natom_threads = batch * natoms;
    bin_kernel<<<(natom_threads + 255) / 256, 256, 0, stream>>>(
        coords, num, off, bins, counts, batch, natoms);

    gather_kernel<<<batch * BOX * NYT, 256, 0, stream>>>(bins, counts, out);
}

// Round 8
// 320.380 us; speedup vs baseline: 1.1463x; 1.0117x over previous
//
#include <hip/hip_runtime.h>

// TypedCoords2Volume — LDS-accumulate gather.
// zero bin counters -> bin atoms by (x,y) 4x4 bins -> gather:
// block = (b, x, 8-row y-tile). Staged atoms scattered into an LDS tile
// [11 types][8 y][120 z] via LDS atomicAdd over their real 5x5 (y,z)
// footprint (~500 __expf evals/block), then the tile is streamed to global
// as contiguous aligned float4 chunks (3840B per type). Every 128B line of
// the 304MB output is written exactly once, fully, by one block.

#define BOX    120
#define NTYPES 11
#define DHALF  2
#define BOX3   (BOX * BOX * BOX)

#define BINSZ  4
#define NBIN   30              // BOX / BINSZ
#define NBIN2  (NBIN * NBIN)
#define CAP    64              // atoms per (x,y) bin column

#define YT     8               // y-rows per gather block
#define NYT    (BOX / YT)      // 15
#define SCAP   192             // staged atoms per block (avg ~21, Poisson-safe)
#define TILEF  (NTYPES * YT * BOX)   // 10560 floats = 42240 B

// ---------------------------------------------------------------------------
__global__ void zero_counts_kernel(int* __restrict__ counts, int n) {
    int i = blockIdx.x * blockDim.x + threadIdx.x;
    if (i < n) counts[i] = 0;
}

// ---------------------------------------------------------------------------
// Bin atoms (unchanged from validated r2/r4 kernel).
// ---------------------------------------------------------------------------
__global__ void bin_kernel(const float* __restrict__ coords,
                           const int*  __restrict__ num_atoms_of_type,
                           const int*  __restrict__ offsets,
                           float4* __restrict__ bins,
                           int*    __restrict__ counts,
                           int batch, int natoms) {
    int gid = blockIdx.x * blockDim.x + threadIdx.x;
    if (gid >= batch * natoms) return;
    int b = gid / natoms;
    int i = gid - b * natoms;

    const float* c = coords + ((long long)b * natoms + i) * 3;
    float x = c[0], y = c[1], z = c[2];

    const int* off = offsets           + b * NTYPES;
    const int* num = num_atoms_of_type + b * NTYPES;

    int t = 0;
#pragma unroll
    for (int k = 1; k < NTYPES; ++k)
        if (off[k] <= i) t = k;
    if (!(i >= off[t] && i < off[t] + num[t])) return;

    int bx = (int)floorf(x);
    int by = (int)floorf(y);
    int bz = (int)floorf(z);
    if (bx < -DHALF || bx >= BOX + DHALF ||
        by < -DHALF || by >= BOX + DHALF ||
        bz < -DHALF || bz >= BOX + DHALF) return;

    int cbx = min(BOX - 1, max(0, bx)) / BINSZ;
    int cby = min(BOX - 1, max(0, by)) / BINSZ;
    int bin = b * NBIN2 + cbx * NBIN + cby;

    int slot = atomicAdd(&counts[bin], 1);
    if (slot < CAP)
        bins[(long long)bin * CAP + slot] =
            make_float4(x, y, z, __int_as_float(t));
}

// ---------------------------------------------------------------------------
// Gather. Block = (b, x, yt). 256 threads.
// ---------------------------------------------------------------------------
__global__ __launch_bounds__(256)
void gather_kernel(const float4* __restrict__ bins,
                   const int*    __restrict__ counts,
                   float* __restrict__ out) {
    int bid = blockIdx.x;
    int yt = bid % NYT; bid /= NYT;
    int x  = bid % BOX; bid /= BOX;
    int b  = bid;
    int y0 = yt * YT;
    float xf = (float)x;

    __shared__ __align__(16) float tile[TILEF];   // [type][yl][z]
    __shared__ float4 srt[SCAP];                  // (ay, az, dx^2, type)
    __shared__ int cnt;

    float4* t4 = reinterpret_cast<float4*>(tile);
    for (int i = threadIdx.x; i < TILEF / 4; i += 256)
        t4[i] = make_float4(0.f, 0.f, 0.f, 0.f);
    if (threadIdx.x == 0) cnt = 0;
    __syncthreads();

    // ---- stage candidate atoms from the <=2x3 neighboring bins ----
    int bxlo = max(0, x - DHALF) / BINSZ;
    int bxhi = min(BOX - 1, x + DHALF) / BINSZ;
    int bylo = max(0, y0 - DHALF) / BINSZ;
    int byhi = min(BOX - 1, y0 + YT - 1 + DHALF) / BINSZ;

    for (int cbx = bxlo; cbx <= bxhi; ++cbx) {
        for (int cby = bylo; cby <= byhi; ++cby) {
            int bin = b * NBIN2 + cbx * NBIN + cby;
            int c = min(counts[bin], CAP);
            const float4* lst = bins + (long long)bin * CAP;
            for (int j = threadIdx.x; j < c; j += 256) {
                float4 a = lst[j];
                float abx = floorf(a.x);
                float aby = floorf(a.y);
                if (fabsf(xf - abx) <= (float)DHALF &&
                    aby >= (float)(y0 - DHALF) &&
                    aby <= (float)(y0 + YT - 1 + DHALF)) {
                    int slot = atomicAdd(&cnt, 1);
                    if (slot < SCAP) {
                        float dx = xf - a.x;
                        srt[slot] = make_float4(a.y, a.z, dx * dx, a.w);
                    }
                }
            }
        }
    }
    __syncthreads();
    int n = min(cnt, SCAP);

    // ---- scatter: one item per (atom, 5y x 5z window voxel) ----
    for (int w = threadIdx.x; w < n * 25; w += 256) {
        int j   = w / 25;
        int rem = w - j * 25;
        int iy  = rem / 5;
        int iz  = rem - iy * 5;
        float4 a = srt[j];
        float ay = a.x, az = a.y, dx2 = a.z;
        int t   = __float_as_int(a.w);
        int aby = (int)floorf(ay);
        int abz = (int)floorf(az);
        int cy  = aby + iy - DHALF;
        int cz  = abz + iz - DHALF;
        if (cy < y0 || cy >= y0 + YT || (unsigned)cz >= (unsigned)BOX) continue;
        float dy = (float)cy - ay;
        float dz = (float)cz - az;
        float r2 = fmaf(dy, dy, fmaf(dz, dz, dx2));
        float v  = __expf(-r2);
        atomicAdd(&tile[(t * YT + (cy - y0)) * BOX + cz], v);
    }
    __syncthreads();

    // ---- stream tile to global: 11 contiguous 3840B chunks, aligned ----
    long long obase = (long long)b * NTYPES * BOX3
                    + (long long)x * (BOX * BOX) + (long long)y0 * BOX;
    for (int i = threadIdx.x; i < NTYPES * 240; i += 256) {
        int k = i / 240;            // type
        int r = i - k * 240;        // float4 index within the 960-float tile
        float4 v = t4[k * 240 + r];
        *reinterpret_cast<float4*>(&out[obase + (long long)k * BOX3 + r * 4]) = v;
    }
}

// ---------------------------------------------------------------------------
extern "C" void kernel_launch(void* const* d_in, const int* in_sizes, int n_in,
                              void* d_out, int out_size, void* d_ws, size_t ws_size,
                              hipStream_t stream) {
    const float* coords = (const float*)d_in[0];
    const int*   num    = (const int*)d_in[1];
    const int*   off    = (const int*)d_in[2];
    float*       out    = (float*)d_out;

    int batch  = in_sizes[1] / NTYPES;        // [B, NTYPES]
    int natoms = in_sizes[0] / (3 * batch);   // [B, NATOMS*3]

    int    nbins  = batch * NBIN2;
    int*   counts = (int*)d_ws;
    size_t bins_off = ((size_t)nbins * sizeof(int) + 15) & ~(size_t)15;
    float4* bins  = (float4*)((char*)d_ws + bins_off);

    zero_counts_kernel<<<(nbins + 255) / 256, 256, 0, stream>>>(counts, nbins);

    int natom_threads = batch * natoms;
    bin_kernel<<<(natom_threads + 255) / 256, 256, 0, stream>>>(
        coords, num, off, bins, counts, batch, natoms);

    gather_kernel<<<batch * BOX * NYT, 256, 0, stream>>>(bins, counts, out);
}

// Round 9
// 310.724 us; speedup vs baseline: 1.1819x; 1.0311x over previous
//
#include <hip/hip_runtime.h>

// TypedCoords2Volume — LDS-accumulate gather, occupancy-tuned.
// memset bin counters -> bin atoms by (x,y) 4x4 bins -> gather:
// block = (b, x, 4-row y-tile), LDS tile [11][4][120] (21 KB -> 6 blocks/CU).
// Staged atoms scatter their exact 5x5 (y,z) footprint into the tile via LDS
// atomicAdd (~350 __expf items/block), then the tile streams to global with
// non-temporal float4 stores (output is never re-read). Every 128B line of
// the 304MB output is written exactly once, fully, by one block.

#define BOX    120
#define NTYPES 11
#define DHALF  2
#define BOX3   (BOX * BOX * BOX)

#define BINSZ  4
#define NBIN   30              // BOX / BINSZ
#define NBIN2  (NBIN * NBIN)
#define CAP    64              // atoms per (x,y) bin column

#define YT     4               // y-rows per gather block
#define NYT    (BOX / YT)      // 30
#define SCAP   128             // staged atoms per block (avg ~14)
#define TILEF  (NTYPES * YT * BOX)   // 5280 floats = 21120 B

typedef float v4f __attribute__((ext_vector_type(4)));

// ---------------------------------------------------------------------------
// Bin atoms (validated r2/r4/r8 logic).
// ---------------------------------------------------------------------------
__global__ void bin_kernel(const float* __restrict__ coords,
                           const int*  __restrict__ num_atoms_of_type,
                           const int*  __restrict__ offsets,
                           float4* __restrict__ bins,
                           int*    __restrict__ counts,
                           int batch, int natoms) {
    int gid = blockIdx.x * blockDim.x + threadIdx.x;
    if (gid >= batch * natoms) return;
    int b = gid / natoms;
    int i = gid - b * natoms;

    const float* c = coords + ((long long)b * natoms + i) * 3;
    float x = c[0], y = c[1], z = c[2];

    const int* off = offsets           + b * NTYPES;
    const int* num = num_atoms_of_type + b * NTYPES;

    int t = 0;
#pragma unroll
    for (int k = 1; k < NTYPES; ++k)
        if (off[k] <= i) t = k;
    if (!(i >= off[t] && i < off[t] + num[t])) return;

    int bx = (int)floorf(x);
    int by = (int)floorf(y);
    int bz = (int)floorf(z);
    if (bx < -DHALF || bx >= BOX + DHALF ||
        by < -DHALF || by >= BOX + DHALF ||
        bz < -DHALF || bz >= BOX + DHALF) return;

    int cbx = min(BOX - 1, max(0, bx)) / BINSZ;
    int cby = min(BOX - 1, max(0, by)) / BINSZ;
    int bin = b * NBIN2 + cbx * NBIN + cby;

    int slot = atomicAdd(&counts[bin], 1);
    if (slot < CAP)
        bins[(long long)bin * CAP + slot] =
            make_float4(x, y, z, __int_as_float(t));
}

// ---------------------------------------------------------------------------
// Gather. Block = (b, x, yt). 256 threads. 6 blocks/CU (21KB tile).
// ---------------------------------------------------------------------------
__global__ __launch_bounds__(256)
void gather_kernel(const float4* __restrict__ bins,
                   const int*    __restrict__ counts,
                   float* __restrict__ out) {
    int bid = blockIdx.x;
    int yt = bid % NYT; bid /= NYT;
    int x  = bid % BOX; bid /= BOX;
    int b  = bid;
    int y0 = yt * YT;
    float xf = (float)x;

    __shared__ __align__(16) float tile[TILEF];   // [type][yl][z]
    __shared__ float4 srt[SCAP];                  // (ay, az, dx^2, type)
    __shared__ int cnt;

    float4* t4 = reinterpret_cast<float4*>(tile);
    for (int i = threadIdx.x; i < TILEF / 4; i += 256)
        t4[i] = make_float4(0.f, 0.f, 0.f, 0.f);
    if (threadIdx.x == 0) cnt = 0;
    __syncthreads();

    // ---- stage candidate atoms from the <=2x3 neighboring bins ----
    int bxlo = max(0, x - DHALF) / BINSZ;
    int bxhi = min(BOX - 1, x + DHALF) / BINSZ;
    int bylo = max(0, y0 - DHALF) / BINSZ;
    int byhi = min(BOX - 1, y0 + YT - 1 + DHALF) / BINSZ;

    for (int cbx = bxlo; cbx <= bxhi; ++cbx) {
        for (int cby = bylo; cby <= byhi; ++cby) {
            int bin = b * NBIN2 + cbx * NBIN + cby;
            int c = min(counts[bin], CAP);
            const float4* lst = bins + (long long)bin * CAP;
            for (int j = threadIdx.x; j < c; j += 256) {
                float4 a = lst[j];
                float abx = floorf(a.x);
                float aby = floorf(a.y);
                if (fabsf(xf - abx) <= (float)DHALF &&
                    aby >= (float)(y0 - DHALF) &&
                    aby <= (float)(y0 + YT - 1 + DHALF)) {
                    int slot = atomicAdd(&cnt, 1);
                    if (slot < SCAP) {
                        float dx = xf - a.x;
                        srt[slot] = make_float4(a.y, a.z, dx * dx, a.w);
                    }
                }
            }
        }
    }
    __syncthreads();
    int n = min(cnt, SCAP);

    // ---- scatter: one item per (atom, 5y x 5z window voxel) ----
    for (int w = threadIdx.x; w < n * 25; w += 256) {
        int j   = w / 25;
        int rem = w - j * 25;
        int iy  = rem / 5;
        int iz  = rem - iy * 5;
        float4 a = srt[j];
        float ay = a.x, az = a.y, dx2 = a.z;
        int t   = __float_as_int(a.w);
        int aby = (int)floorf(ay);
        int abz = (int)floorf(az);
        int cy  = aby + iy - DHALF;
        int cz  = abz + iz - DHALF;
        if (cy < y0 || cy >= y0 + YT || (unsigned)cz >= (unsigned)BOX) continue;
        float dy = (float)cy - ay;
        float dz = (float)cz - az;
        float r2 = fmaf(dy, dy, fmaf(dz, dz, dx2));
        float v  = __expf(-r2);
        atomicAdd(&tile[(t * YT + (cy - y0)) * BOX + cz], v);
    }
    __syncthreads();

    // ---- stream tile to global: 11 contiguous 1920B chunks, aligned,
    //      non-temporal (output is write-once, never re-read) ----
    long long obase = (long long)b * NTYPES * BOX3
                    + (long long)x * (BOX * BOX) + (long long)y0 * BOX;
    const v4f* t4v = reinterpret_cast<const v4f*>(tile);
    const int C4 = YT * BOX / 4;                 // 120 float4 per type chunk
    for (int i = threadIdx.x; i < NTYPES * C4; i += 256) {
        int k = i / C4;             // type
        int r = i - k * C4;         // float4 index within chunk
        v4f v = t4v[k * C4 + r];
        __builtin_nontemporal_store(
            v, reinterpret_cast<v4f*>(&out[obase + (long long)k * BOX3 + r * 4]));
    }
}

// ---------------------------------------------------------------------------
extern "C" void kernel_launch(void* const* d_in, const int* in_sizes, int n_in,
                              void* d_out, int out_size, void* d_ws, size_t ws_size,
                              hipStream_t stream) {
    const float* coords = (const float*)d_in[0];
    const int*   num    = (const int*)d_in[1];
    const int*   off    = (const int*)d_in[2];
    float*       out    = (float*)d_out;

    int batch  = in_sizes[1] / NTYPES;        // [B, NTYPES]
    int natoms = in_sizes[0] / (3 * batch);   // [B, NATOMS*3]

    int    nbins  = batch * NBIN2;
    int*   counts = (int*)d_ws;
    size_t bins_off = ((size_t)nbins * sizeof(int) + 15) & ~(size_t)15;
    float4* bins  = (float4*)((char*)d_ws + bins_off);

    // zero bin counters via memset node (one fewer kernel dispatch)
    hipMemsetAsync(counts, 0, (size_t)nbins * sizeof(int), stream);

    int natom_threads = batch * natoms;
    bin_kernel<<<(natom_threads + 255) / 256, 256, 0, stream>>>(
        coords, num, off, bins, counts, batch, natoms);

    gather_kernel<<<batch * BOX * NYT, 256, 0, stream>>>(bins, counts, out);
}